// Round 3
// baseline (1738.821 us; speedup 1.0000x reference)
//
#include <hip/hip_runtime.h>

#define V_N   200000
#define E_N   600000
#define FEAT  960
#define HDIM  128
#define NREST 7
#define NSCAN 196   // ceil(V_N/1024)

typedef __attribute__((ext_vector_type(8))) short bf16x8;
typedef __attribute__((ext_vector_type(4))) float f32x4;

__device__ __forceinline__ unsigned short f2bf(float f) {
    unsigned u = __builtin_bit_cast(unsigned, f);
    unsigned r = (u + 0x7FFFu + ((u >> 16) & 1u)) >> 16;
    return (unsigned short)r;
}
__device__ __forceinline__ float bf2f(unsigned h) {
    unsigned u = h << 16;
    return __builtin_bit_cast(float, u);
}

// ---------------------------------------------------------------------------
// Backbone MFMA GEMM: C = relu(A(fp32) @ B^T + bias), BM=BN=128, BK=64.
// 256 threads = 4 waves 2x2, each wave 64x64 (4x4 16x16 frags).
// LDS XOR-swizzle (elem ^ ((row&7)<<3)) on write and read.
// ---------------------------------------------------------------------------
template<int KT>
__global__ __launch_bounds__(256) void backbone_mfma_kernel(
    const float* __restrict__ A, int lda,
    const short* __restrict__ B, int ldb,
    const float* __restrict__ bias,
    short* __restrict__ C, int ldc)
{
    __shared__ short As[128 * 64];
    __shared__ short Bs[128 * 64];
    const int tid = threadIdx.x;
    const int bm0 = blockIdx.x * 128;
    const int wid = tid >> 6, lane = tid & 63;
    const int wm = wid >> 1, wn = wid & 1;

    f32x4 acc[4][4];
    #pragma unroll
    for (int n = 0; n < 4; ++n) {
        float bv = bias[wn * 64 + n * 16 + (lane & 15)];
        #pragma unroll
        for (int m = 0; m < 4; ++m)
            acc[m][n] = (f32x4){bv, bv, bv, bv};
    }

    for (int it = 0; it < KT; ++it) {
        const int k0 = it * 64;
        __syncthreads();
        // ---- stage A tile [128][64] fp32 -> bf16 ----
        #pragma unroll
        for (int i = 0; i < 8; ++i) {
            int c = i * 256 + tid;          // 2048 float4 chunks
            int row = c >> 4, c4 = c & 15;
            int grow = bm0 + row; if (grow >= V_N) grow = V_N - 1;
            float4 t = *(const float4*)(A + (size_t)grow * lda + k0 + c4 * 4);
            unsigned lo = (unsigned)f2bf(t.x) | ((unsigned)f2bf(t.y) << 16);
            unsigned hi = (unsigned)f2bf(t.z) | ((unsigned)f2bf(t.w) << 16);
            int e = (row * 64 + c4 * 4) ^ ((row & 7) << 3);
            *(uint2*)&As[e] = make_uint2(lo, hi);
        }
        // ---- stage B tile [128][64] ----
        #pragma unroll
        for (int i = 0; i < 4; ++i) {
            int c = i * 256 + tid;
            int row = c >> 3, c8 = c & 7;
            float4 t = *(const float4*)(B + (size_t)row * ldb + k0 + c8 * 8);
            int e = (row * 64 + c8 * 8) ^ ((row & 7) << 3);
            *(float4*)&Bs[e] = t;
        }
        __syncthreads();
        #pragma unroll
        for (int kk = 0; kk < 2; ++kk) {
            bf16x8 a[4], b[4];
            #pragma unroll
            for (int m = 0; m < 4; ++m) {
                int row = wm * 64 + m * 16 + (lane & 15);
                int e = (row * 64 + kk * 32 + (lane >> 4) * 8) ^ ((row & 7) << 3);
                a[m] = *(const bf16x8*)&As[e];
            }
            #pragma unroll
            for (int n = 0; n < 4; ++n) {
                int row = wn * 64 + n * 16 + (lane & 15);
                int e = (row * 64 + kk * 32 + (lane >> 4) * 8) ^ ((row & 7) << 3);
                b[n] = *(const bf16x8*)&Bs[e];
            }
            #pragma unroll
            for (int m = 0; m < 4; ++m)
                #pragma unroll
                for (int n = 0; n < 4; ++n)
                    acc[m][n] = __builtin_amdgcn_mfma_f32_16x16x32_bf16(
                        a[m], b[n], acc[m][n], 0, 0, 0);
        }
    }

    #pragma unroll
    for (int m = 0; m < 4; ++m) {
        int rbase = bm0 + wm * 64 + m * 16 + (lane >> 4) * 4;
        #pragma unroll
        for (int j = 0; j < 4; ++j) {
            int grow = rbase + j;
            if (grow < V_N) {
                #pragma unroll
                for (int n = 0; n < 4; ++n) {
                    float v = fmaxf(acc[m][n][j], 0.f);
                    C[(size_t)grow * ldc + wn * 64 + n * 16 + (lane & 15)] =
                        (short)f2bf(v);
                }
            }
        }
    }
}

// ---------------------------------------------------------------------------
// GraphConv fused GEMM:
//   C[v] = relu( [A0[v] | A1[v]] @ B^T + b0 + deg[v]*b1 ),  N=128.
// A0 = x (self), A1 = s (neighbor sum). K = (T0+T1)*64. In-place safe (C==A0):
// each block reads only the rows it writes; all global A reads complete
// before the epilogue (barrier-separated staging).
// ---------------------------------------------------------------------------
template<int T0, int T1>
__global__ __launch_bounds__(256) void gconv_mfma_kernel(
    const short* __restrict__ A0, int lda0,
    const short* __restrict__ A1, int lda1,
    const short* __restrict__ B,               // [128][(T0+T1)*64] bf16
    const float* __restrict__ b0, const float* __restrict__ b1,
    const int* __restrict__ deg,
    short* __restrict__ C)                     // [V][128] bf16
{
    constexpr int KT = T0 + T1;
    constexpr int KB = KT * 64;
    __shared__ short As[128 * 64];
    __shared__ short Bs[128 * 64];
    const int tid = threadIdx.x;
    const int bm0 = blockIdx.x * 128;
    const int wid = tid >> 6, lane = tid & 63;
    const int wm = wid >> 1, wn = wid & 1;

    f32x4 acc[4][4] = {};

    for (int it = 0; it < KT; ++it) {
        const short* Ap; int lda, k0;
        if (it < T0) { Ap = A0; lda = lda0; k0 = it * 64; }
        else         { Ap = A1; lda = lda1; k0 = (it - T0) * 64; }
        __syncthreads();
        #pragma unroll
        for (int i = 0; i < 4; ++i) {
            int c = i * 256 + tid;
            int row = c >> 3, c8 = c & 7;
            int grow = bm0 + row; if (grow >= V_N) grow = V_N - 1;
            float4 t = *(const float4*)(Ap + (size_t)grow * lda + k0 + c8 * 8);
            int e = (row * 64 + c8 * 8) ^ ((row & 7) << 3);
            *(float4*)&As[e] = t;
        }
        const int kb0 = it * 64;
        #pragma unroll
        for (int i = 0; i < 4; ++i) {
            int c = i * 256 + tid;
            int row = c >> 3, c8 = c & 7;
            float4 t = *(const float4*)(B + (size_t)row * KB + kb0 + c8 * 8);
            int e = (row * 64 + c8 * 8) ^ ((row & 7) << 3);
            *(float4*)&Bs[e] = t;
        }
        __syncthreads();
        #pragma unroll
        for (int kk = 0; kk < 2; ++kk) {
            bf16x8 a[4], b[4];
            #pragma unroll
            for (int m = 0; m < 4; ++m) {
                int row = wm * 64 + m * 16 + (lane & 15);
                int e = (row * 64 + kk * 32 + (lane >> 4) * 8) ^ ((row & 7) << 3);
                a[m] = *(const bf16x8*)&As[e];
            }
            #pragma unroll
            for (int n = 0; n < 4; ++n) {
                int row = wn * 64 + n * 16 + (lane & 15);
                int e = (row * 64 + kk * 32 + (lane >> 4) * 8) ^ ((row & 7) << 3);
                b[n] = *(const bf16x8*)&Bs[e];
            }
            #pragma unroll
            for (int m = 0; m < 4; ++m)
                #pragma unroll
                for (int n = 0; n < 4; ++n)
                    acc[m][n] = __builtin_amdgcn_mfma_f32_16x16x32_bf16(
                        a[m], b[n], acc[m][n], 0, 0, 0);
        }
    }

    // epilogue: bias = b0[col] + deg[row]*b1[col], relu, bf16 store
    #pragma unroll
    for (int m = 0; m < 4; ++m) {
        int rbase = bm0 + wm * 64 + m * 16 + (lane >> 4) * 4;
        #pragma unroll
        for (int j = 0; j < 4; ++j) {
            int grow = rbase + j;
            if (grow < V_N) {
                float dv = (float)deg[grow];
                #pragma unroll
                for (int n = 0; n < 4; ++n) {
                    int colx = wn * 64 + n * 16 + (lane & 15);
                    float v = acc[m][n][j] + b0[colx] + dv * b1[colx];
                    v = fmaxf(v, 0.f);
                    C[(size_t)grow * 128 + colx] = (short)f2bf(v);
                }
            }
        }
    }
}

// ---------------------------------------------------------------------------
// Neighbor sum: s[v] = sum_{u in adj(v)} x[u]   (bf16 in/out, fp32 accum)
// One wave per vertex; NU = uints (2 bf16) per row.
// ---------------------------------------------------------------------------
template<int NU>
__global__ __launch_bounds__(256) void agg_sum_kernel(
    const short* __restrict__ x, const int* __restrict__ rowp,
    const int* __restrict__ col, short* __restrict__ s)
{
    int wid  = (blockIdx.x * blockDim.x + threadIdx.x) >> 6;
    int lane = threadIdx.x & 63;
    if (wid >= V_N) return;
    float a0 = 0.f, a1 = 0.f, c0 = 0.f, c1 = 0.f;
    const bool second = (NU > 64) && (lane < NU - 64);
    int st = rowp[wid], en = rowp[wid + 1];
    for (int p = st; p < en; ++p) {
        int u = col[p];
        const unsigned* r = (const unsigned*)(x + (size_t)u * (NU * 2));
        unsigned q = r[lane];
        a0 += bf2f(q & 0xffffu); a1 += bf2f(q >> 16);
        if (NU > 64 && second) {
            unsigned q2 = r[lane + 64];
            c0 += bf2f(q2 & 0xffffu); c1 += bf2f(q2 >> 16);
        }
    }
    unsigned* so = (unsigned*)(s + (size_t)wid * (NU * 2));
    so[lane] = (unsigned)f2bf(a0) | ((unsigned)f2bf(a1) << 16);
    if (NU > 64 && second)
        so[lane + 64] = (unsigned)f2bf(c0) | ((unsigned)f2bf(c1) << 16);
}

// ---------------------------------------------------------------------------
// Final projection: out[v] = x[v] @ vo_W.T + vo_b  (bf16 x, fp32 out, N=3)
// ---------------------------------------------------------------------------
__global__ __launch_bounds__(256) void vout_kernel(
    const short* __restrict__ x, const float* __restrict__ W,
    const float* __restrict__ b, float* __restrict__ out)
{
    int v = blockIdx.x * blockDim.x + threadIdx.x;
    if (v >= V_N) return;
    const short* xin = x + (size_t)v * 128;
    float a0 = b[0], a1 = b[1], a2 = b[2];
    #pragma unroll
    for (int k0 = 0; k0 < 128; k0 += 8) {
        float4 t = *(const float4*)(xin + k0);
        const unsigned* u = (const unsigned*)&t;
        #pragma unroll
        for (int q = 0; q < 4; ++q) {
            float xl = bf2f(u[q] & 0xffffu), xh = bf2f(u[q] >> 16);
            int k = k0 + q * 2;
            a0 += xl * W[k]       + xh * W[k + 1];
            a1 += xl * W[128 + k] + xh * W[129 + k];
            a2 += xl * W[256 + k] + xh * W[257 + k];
        }
    }
    out[3 * v]     = a0;
    out[3 * v + 1] = a1;
    out[3 * v + 2] = a2;
}

// ------------------------- weight / input prep ----------------------------
__global__ void prep_bn_kernel(const float* __restrict__ W, short* __restrict__ Wb)
{
    int i = blockIdx.x * 256 + threadIdx.x;
    if (i < 128 * FEAT) Wb[i] = (short)f2bf(W[i]);
}

// layer0 weights: [128][384]: cols 0..191 = W0 (131 real, pad0), 192..383 = W1
__global__ void prep_w0_kernel(const float* __restrict__ W0,
                               const float* __restrict__ W1,
                               short* __restrict__ Wc)
{
    int i = blockIdx.x * 256 + threadIdx.x;
    if (i >= 128 * 384) return;
    int r = i / 384, c = i % 384;
    float v = 0.f;
    if (c < 192) { if (c < 131) v = W0[r * 131 + c]; }
    else         { int cc = c - 192; if (cc < 131) v = W1[r * 131 + cc]; }
    Wc[i] = (short)f2bf(v);
}

// layers 1..7: [7][128][256]: cols 0..127 = W0, 128..255 = W1
__global__ void prep_wl_kernel(const float* __restrict__ gW0,
                               const float* __restrict__ gW1,
                               short* __restrict__ Wc)
{
    int i = blockIdx.x * 256 + threadIdx.x;
    if (i >= NREST * 128 * 256) return;
    int l = i / (128 * 256), r = (i / 256) % 128, c = i % 256;
    float v = (c < 128) ? gW0[(l * 128 + r) * 128 + c]
                        : gW1[(l * 128 + r) * 128 + (c - 128)];
    Wc[i] = (short)f2bf(v);
}

__global__ void pad_x0_kernel(const float* __restrict__ verts, short* __restrict__ x0)
{
    int v = blockIdx.x * blockDim.x + threadIdx.x;
    if (v >= V_N) return;
    short* row = x0 + (size_t)v * 192;
    row[128] = (short)f2bf(verts[3 * v]);
    row[129] = (short)f2bf(verts[3 * v + 1]);
    row[130] = (short)f2bf(verts[3 * v + 2]);
    #pragma unroll
    for (int c = 131; c < 192; ++c) row[c] = 0;
}

// ------------------------- CSR construction -------------------------------
__global__ void deg_count_kernel(const int* __restrict__ edges, int* __restrict__ deg)
{
    int e = blockIdx.x * blockDim.x + threadIdx.x;
    if (e >= E_N) return;
    int i = edges[2 * e], j = edges[2 * e + 1];
    atomicAdd(&deg[i], 1);
    atomicAdd(&deg[j], 1);
}

__global__ __launch_bounds__(1024) void scan_block_kernel(
    const int* __restrict__ deg, int* __restrict__ excl, int* __restrict__ bsum)
{
    __shared__ int sdata[1024];
    int t = threadIdx.x;
    int base = blockIdx.x * 1024;
    int val = (base + t < V_N) ? deg[base + t] : 0;
    sdata[t] = val; __syncthreads();
    for (int off = 1; off < 1024; off <<= 1) {
        int tmp = (t >= off) ? sdata[t - off] : 0;
        __syncthreads();
        sdata[t] += tmp;
        __syncthreads();
    }
    if (base + t < V_N) excl[base + t] = sdata[t] - val;
    if (t == 1023) bsum[blockIdx.x] = sdata[1023];
}

__global__ __launch_bounds__(256) void scan_bsum_kernel(
    const int* __restrict__ bsum, int* __restrict__ boff)
{
    __shared__ int sdata[256];
    int t = threadIdx.x;
    int val = (t < NSCAN) ? bsum[t] : 0;
    sdata[t] = val; __syncthreads();
    for (int off = 1; off < 256; off <<= 1) {
        int tmp = (t >= off) ? sdata[t - off] : 0;
        __syncthreads();
        sdata[t] += tmp;
        __syncthreads();
    }
    if (t < NSCAN) boff[t] = sdata[t] - val;
    if (t == 255) boff[NSCAN] = sdata[255];
}

__global__ void scan_add_kernel(const int* __restrict__ boff,
                                int* __restrict__ rowp, int* __restrict__ cur)
{
    int i = blockIdx.x * blockDim.x + threadIdx.x;
    if (i < V_N) {
        int r = rowp[i] + boff[i >> 10];
        rowp[i] = r;
        cur[i] = r;
    } else if (i == V_N) {
        rowp[V_N] = boff[NSCAN];
    }
}

__global__ void fill_kernel(const int* __restrict__ edges,
                            int* __restrict__ cur, int* __restrict__ col)
{
    int e = blockIdx.x * blockDim.x + threadIdx.x;
    if (e >= E_N) return;
    int i = edges[2 * e], j = edges[2 * e + 1];
    col[atomicAdd(&cur[i], 1)] = j;
    col[atomicAdd(&cur[j], 1)] = i;
}

// ---------------------------------------------------------------------------
extern "C" void kernel_launch(void* const* d_in, const int* in_sizes, int n_in,
                              void* d_out, int out_size, void* d_ws, size_t ws_size,
                              hipStream_t stream)
{
    const float* img   = (const float*)d_in[0];
    const float* verts = (const float*)d_in[1];
    const int*   edges = (const int*)  d_in[2];
    const float* bnW   = (const float*)d_in[3];
    const float* bnb   = (const float*)d_in[4];
    const float* g0W0  = (const float*)d_in[5];
    const float* g0b0  = (const float*)d_in[6];
    const float* g0W1  = (const float*)d_in[7];
    const float* g0b1  = (const float*)d_in[8];
    const float* gW0   = (const float*)d_in[9];
    const float* gb0   = (const float*)d_in[10];
    const float* gW1   = (const float*)d_in[11];
    const float* gb1   = (const float*)d_in[12];
    const float* voW   = (const float*)d_in[13];
    const float* vob   = (const float*)d_in[14];
    float* out = (float*)d_out;

    // workspace layout (all segment byte counts multiples of 16)
    short* x0   = (short*)d_ws;                       // V*192 bf16
    short* s0   = x0   + (size_t)V_N * 192;           // V*192 bf16
    short* xb   = s0   + (size_t)V_N * 192;           // V*128 bf16
    short* sb   = xb   + (size_t)V_N * 128;           // V*128 bf16
    short* bnWb = sb   + (size_t)V_N * 128;           // 128*960
    short* Wc0  = bnWb + 128 * FEAT;                  // 128*384
    short* Wcl  = Wc0  + 128 * 384;                   // 7*128*256
    int*   deg  = (int*)(Wcl + NREST * 128 * 256);    // V
    int*   rowp = deg  + V_N;                         // V+1
    int*   cur  = rowp + V_N + 1;                     // V
    int*   bsum = cur  + V_N;                         // 256
    int*   boff = bsum + 256;                         // NSCAN+1
    int*   col  = boff + 257;                         // 2E

    // ---- CSR build ----
    hipMemsetAsync(deg, 0, V_N * sizeof(int), stream);
    deg_count_kernel<<<(E_N + 255) / 256, 256, 0, stream>>>(edges, deg);
    scan_block_kernel<<<NSCAN, 1024, 0, stream>>>(deg, rowp, bsum);
    scan_bsum_kernel<<<1, 256, 0, stream>>>(bsum, boff);
    scan_add_kernel<<<(V_N + 256) / 256, 256, 0, stream>>>(boff, rowp, cur);
    fill_kernel<<<(E_N + 255) / 256, 256, 0, stream>>>(edges, cur, col);

    // ---- weight / x0 prep ----
    prep_bn_kernel<<<(128 * FEAT + 255) / 256, 256, 0, stream>>>(bnW, bnWb);
    prep_w0_kernel<<<(128 * 384 + 255) / 256, 256, 0, stream>>>(g0W0, g0W1, Wc0);
    prep_wl_kernel<<<(NREST * 128 * 256 + 255) / 256, 256, 0, stream>>>(gW0, gW1, Wcl);
    pad_x0_kernel<<<(V_N + 255) / 256, 256, 0, stream>>>(verts, x0);

    const int MB = (V_N + 127) / 128;   // 1563

    // ---- backbone: img(fp32,K=960) @ bnW^T -> x0 cols 0..127 (relu) ----
    backbone_mfma_kernel<15><<<MB, 256, 0, stream>>>(img, FEAT, bnWb, FEAT, bnb, x0, 192);

    // ---- layer 0: s0 = neighbor-sum(x0); x = relu([x0|s0]@Wc0^T + b0 + deg*b1) ----
    agg_sum_kernel<96><<<(V_N * 64 + 255) / 256, 256, 0, stream>>>(x0, rowp, col, s0);
    gconv_mfma_kernel<3, 3><<<MB, 256, 0, stream>>>(
        x0, 192, s0, 192, Wc0, g0b0, g0b1, deg, xb);

    // ---- layers 1..7 (GEMM in-place on xb) ----
    for (int l = 0; l < NREST; ++l) {
        agg_sum_kernel<64><<<(V_N * 64 + 255) / 256, 256, 0, stream>>>(xb, rowp, col, sb);
        gconv_mfma_kernel<2, 2><<<MB, 256, 0, stream>>>(
            xb, 128, sb, 128, Wcl + (size_t)l * 128 * 256,
            gb0 + (size_t)l * 128, gb1 + (size_t)l * 128, deg, xb);
    }

    // ---- final projection ----
    vout_kernel<<<(V_N + 255) / 256, 256, 0, stream>>>(xb, voW, vob, out);
}

// Round 4
// 1297.679 us; speedup vs baseline: 1.3399x; 1.3399x over previous
//
#include <hip/hip_runtime.h>

#define V_N   200000
#define E_N   600000
#define FEAT  960
#define HDIM  128
#define NREST 7
#define NSCAN 196   // ceil(V_N/1024)

typedef __attribute__((ext_vector_type(8))) short bf16x8;
typedef __attribute__((ext_vector_type(4))) float f32x4;

__device__ __forceinline__ unsigned short f2bf(float f) {
    unsigned u = __builtin_bit_cast(unsigned, f);
    unsigned r = (u + 0x7FFFu + ((u >> 16) & 1u)) >> 16;
    return (unsigned short)r;
}
__device__ __forceinline__ float bf2f(unsigned h) {
    unsigned u = h << 16;
    return __builtin_bit_cast(float, u);
}

// async global->LDS, 16B per lane; LDS dest wave-uniform base + lane*16.
__device__ __forceinline__ void gload_lds16(const void* g, void* l) {
    __builtin_amdgcn_global_load_lds(
        (const __attribute__((address_space(1))) void*)g,
        (__attribute__((address_space(3))) void*)l, 16, 0, 0);
}

// ---------------------------------------------------------------------------
// Backbone MFMA GEMM: C = relu(A(fp32) @ B^T + bias), BM=BN=128, BK=64.
// 4 waves 2x2, wave 64x64 (4x4 16x16x32 frags). A reg-staged (f32->bf16),
// B via global_load_lds with source-side XOR swizzle (chunk c8 ^ (row&7)).
// Epilogue: C tile -> LDS (swizzled) -> coalesced uint4 stores.
// ---------------------------------------------------------------------------
template<int KT>
__global__ __launch_bounds__(256) void backbone_mfma_kernel(
    const float* __restrict__ A, int lda,
    const short* __restrict__ B, int ldb,
    const float* __restrict__ bias,
    short* __restrict__ C, int ldc)
{
    __shared__ short Smem[128 * 128];
    short* As = Smem;
    short* Bs = Smem + 128 * 64;
    const int tid = threadIdx.x;
    const int bm0 = blockIdx.x * 128;
    const int wid = tid >> 6, lane = tid & 63;
    const int wm = wid >> 1, wn = wid & 1;
    const int srow = wid * 32 + (lane >> 3);   // staging row (this lane)
    const int sc   = lane & 7;                 // staging chunk

    f32x4 acc[4][4];
    #pragma unroll
    for (int n = 0; n < 4; ++n) {
        float bv = bias[wn * 64 + n * 16 + (lane & 15)];
        #pragma unroll
        for (int m = 0; m < 4; ++m)
            acc[m][n] = (f32x4){bv, bv, bv, bv};
    }

    for (int it = 0; it < KT; ++it) {
        const int k0 = it * 64;
        __syncthreads();
        // ---- stage A tile [128][64] fp32 -> bf16 (register path, swizzled) ----
        #pragma unroll
        for (int i = 0; i < 8; ++i) {
            int c = i * 256 + tid;          // 2048 float4 chunks
            int row = c >> 4, c4 = c & 15;
            int grow = bm0 + row; if (grow >= V_N) grow = V_N - 1;
            float4 t = *(const float4*)(A + (size_t)grow * lda + k0 + c4 * 4);
            unsigned lo = (unsigned)f2bf(t.x) | ((unsigned)f2bf(t.y) << 16);
            unsigned hi = (unsigned)f2bf(t.z) | ((unsigned)f2bf(t.w) << 16);
            int e = (row * 64 + c4 * 4) ^ ((row & 7) << 3);
            *(uint2*)&As[e] = make_uint2(lo, hi);
        }
        // ---- stage B tile [128][64] via global_load_lds ----
        #pragma unroll
        for (int i = 0; i < 4; ++i) {
            int row = srow + i * 8;
            int g = (sc ^ (row & 7)) << 3;
            gload_lds16(B + (size_t)row * ldb + k0 + g, Bs + (wid * 32 + i * 8) * 64);
        }
        __syncthreads();
        #pragma unroll
        for (int kk = 0; kk < 2; ++kk) {
            bf16x8 a[4], b[4];
            #pragma unroll
            for (int m = 0; m < 4; ++m) {
                int row = wm * 64 + m * 16 + (lane & 15);
                int e = (row * 64 + kk * 32 + (lane >> 4) * 8) ^ ((row & 7) << 3);
                a[m] = *(const bf16x8*)&As[e];
            }
            #pragma unroll
            for (int n = 0; n < 4; ++n) {
                int row = wn * 64 + n * 16 + (lane & 15);
                int e = (row * 64 + kk * 32 + (lane >> 4) * 8) ^ ((row & 7) << 3);
                b[n] = *(const bf16x8*)&Bs[e];
            }
            #pragma unroll
            for (int m = 0; m < 4; ++m)
                #pragma unroll
                for (int n = 0; n < 4; ++n)
                    acc[m][n] = __builtin_amdgcn_mfma_f32_16x16x32_bf16(
                        a[m], b[n], acc[m][n], 0, 0, 0);
        }
    }

    // ---- epilogue: relu -> LDS (swizzled) -> coalesced stores ----
    __syncthreads();
    #pragma unroll
    for (int m = 0; m < 4; ++m) {
        #pragma unroll
        for (int j = 0; j < 4; ++j) {
            int row = wm * 64 + m * 16 + (lane >> 4) * 4 + j;
            #pragma unroll
            for (int n = 0; n < 4; ++n) {
                int colx = wn * 64 + n * 16 + (lane & 15);
                float v = fmaxf(acc[m][n][j], 0.f);
                Smem[row * 128 + (((colx >> 3) ^ (row & 7)) << 3) + (colx & 7)] =
                    (short)f2bf(v);
            }
        }
    }
    __syncthreads();
    #pragma unroll
    for (int i = 0; i < 8; ++i) {
        int c = i * 256 + tid;
        int r = c >> 4, c8 = c & 15;
        int grow = bm0 + r;
        if (grow < V_N)
            *(uint4*)&C[(size_t)grow * ldc + c8 * 8] =
                *(const uint4*)&Smem[r * 128 + (c8 ^ (r & 7)) * 8];
    }
}

// ---------------------------------------------------------------------------
// GraphConv fused GEMM:
//   C[v] = relu( [A0[v] | A1[v]] @ B^T + b0 + deg[v]*b1 ),  N=128.
// A/B staged via global_load_lds with source-side swizzle. In-place safe
// (C==A0): each block reads only rows it writes; reads complete pre-epilogue.
// ---------------------------------------------------------------------------
template<int T0, int T1>
__global__ __launch_bounds__(256) void gconv_mfma_kernel(
    const short* __restrict__ A0, int lda0,
    const short* __restrict__ A1, int lda1,
    const short* __restrict__ B,               // [128][(T0+T1)*64] bf16
    const float* __restrict__ b0, const float* __restrict__ b1,
    const int* __restrict__ deg,
    short* __restrict__ C)                     // [V][128] bf16
{
    constexpr int KT = T0 + T1;
    constexpr int KB = KT * 64;
    __shared__ short Smem[128 * 128];
    short* As = Smem;
    short* Bs = Smem + 128 * 64;
    const int tid = threadIdx.x;
    const int bm0 = blockIdx.x * 128;
    const int wid = tid >> 6, lane = tid & 63;
    const int wm = wid >> 1, wn = wid & 1;
    const int srow = wid * 32 + (lane >> 3);
    const int sc   = lane & 7;

    f32x4 acc[4][4] = {};

    for (int it = 0; it < KT; ++it) {
        const short* Ap; int lda, k0;
        if (it < T0) { Ap = A0; lda = lda0; k0 = it * 64; }
        else         { Ap = A1; lda = lda1; k0 = (it - T0) * 64; }
        const int kb0 = it * 64;
        __syncthreads();
        #pragma unroll
        for (int i = 0; i < 4; ++i) {
            int row = srow + i * 8;
            int g = (sc ^ (row & 7)) << 3;
            int grow = bm0 + row; if (grow >= V_N) grow = V_N - 1;
            gload_lds16(Ap + (size_t)grow * lda + k0 + g, As + (wid * 32 + i * 8) * 64);
            gload_lds16(B + (size_t)row * KB + kb0 + g, Bs + (wid * 32 + i * 8) * 64);
        }
        __syncthreads();
        #pragma unroll
        for (int kk = 0; kk < 2; ++kk) {
            bf16x8 a[4], b[4];
            #pragma unroll
            for (int m = 0; m < 4; ++m) {
                int row = wm * 64 + m * 16 + (lane & 15);
                int e = (row * 64 + kk * 32 + (lane >> 4) * 8) ^ ((row & 7) << 3);
                a[m] = *(const bf16x8*)&As[e];
            }
            #pragma unroll
            for (int n = 0; n < 4; ++n) {
                int row = wn * 64 + n * 16 + (lane & 15);
                int e = (row * 64 + kk * 32 + (lane >> 4) * 8) ^ ((row & 7) << 3);
                b[n] = *(const bf16x8*)&Bs[e];
            }
            #pragma unroll
            for (int m = 0; m < 4; ++m)
                #pragma unroll
                for (int n = 0; n < 4; ++n)
                    acc[m][n] = __builtin_amdgcn_mfma_f32_16x16x32_bf16(
                        a[m], b[n], acc[m][n], 0, 0, 0);
        }
    }

    // bias preload (col-only)
    float bb0[4], bb1[4];
    #pragma unroll
    for (int n = 0; n < 4; ++n) {
        int colx = wn * 64 + n * 16 + (lane & 15);
        bb0[n] = b0[colx]; bb1[n] = b1[colx];
    }

    // ---- epilogue: bias+relu -> LDS (swizzled) -> coalesced stores ----
    __syncthreads();
    #pragma unroll
    for (int m = 0; m < 4; ++m) {
        #pragma unroll
        for (int j = 0; j < 4; ++j) {
            int row = wm * 64 + m * 16 + (lane >> 4) * 4 + j;
            int grow = bm0 + row; if (grow >= V_N) grow = V_N - 1;
            float dv = (float)deg[grow];
            #pragma unroll
            for (int n = 0; n < 4; ++n) {
                int colx = wn * 64 + n * 16 + (lane & 15);
                float v = fmaxf(acc[m][n][j] + bb0[n] + dv * bb1[n], 0.f);
                Smem[row * 128 + (((colx >> 3) ^ (row & 7)) << 3) + (colx & 7)] =
                    (short)f2bf(v);
            }
        }
    }
    __syncthreads();
    #pragma unroll
    for (int i = 0; i < 8; ++i) {
        int c = i * 256 + tid;
        int r = c >> 4, c8 = c & 15;
        int grow = bm0 + r;
        if (grow < V_N)
            *(uint4*)&C[(size_t)grow * 128 + c8 * 8] =
                *(const uint4*)&Smem[r * 128 + (c8 ^ (r & 7)) * 8];
    }
}

// ---------------------------------------------------------------------------
// Neighbor sum: s[v] = sum_{u in adj(v)} x[u]  (bf16 io, fp32 accum).
// One wave per vertex; 4-way unrolled independent gathers (MLP not chain).
// ---------------------------------------------------------------------------
template<int NU>
__global__ __launch_bounds__(256) void agg_sum_kernel(
    const short* __restrict__ x, const int* __restrict__ rowp,
    const int* __restrict__ col, short* __restrict__ s)
{
    int wid  = (blockIdx.x * blockDim.x + threadIdx.x) >> 6;
    int lane = threadIdx.x & 63;
    if (wid >= V_N) return;
    float a0 = 0.f, a1 = 0.f, c0 = 0.f, c1 = 0.f;
    const bool second = (NU > 64) && (lane < NU - 64);
    int st = rowp[wid], en = rowp[wid + 1];
    int p = st;
    for (; p + 4 <= en; p += 4) {
        int u0 = col[p], u1 = col[p + 1], u2 = col[p + 2], u3 = col[p + 3];
        const unsigned* r0 = (const unsigned*)(x + (size_t)u0 * (NU * 2));
        const unsigned* r1 = (const unsigned*)(x + (size_t)u1 * (NU * 2));
        const unsigned* r2 = (const unsigned*)(x + (size_t)u2 * (NU * 2));
        const unsigned* r3 = (const unsigned*)(x + (size_t)u3 * (NU * 2));
        unsigned q0 = r0[lane], q1 = r1[lane], q2 = r2[lane], q3 = r3[lane];
        a0 += bf2f(q0 & 0xffffu) + bf2f(q1 & 0xffffu) + bf2f(q2 & 0xffffu) + bf2f(q3 & 0xffffu);
        a1 += bf2f(q0 >> 16) + bf2f(q1 >> 16) + bf2f(q2 >> 16) + bf2f(q3 >> 16);
        if (NU > 64 && second) {
            unsigned t0 = r0[lane + 64], t1 = r1[lane + 64], t2 = r2[lane + 64], t3 = r3[lane + 64];
            c0 += bf2f(t0 & 0xffffu) + bf2f(t1 & 0xffffu) + bf2f(t2 & 0xffffu) + bf2f(t3 & 0xffffu);
            c1 += bf2f(t0 >> 16) + bf2f(t1 >> 16) + bf2f(t2 >> 16) + bf2f(t3 >> 16);
        }
    }
    for (; p < en; ++p) {
        int u = col[p];
        const unsigned* r = (const unsigned*)(x + (size_t)u * (NU * 2));
        unsigned q = r[lane];
        a0 += bf2f(q & 0xffffu); a1 += bf2f(q >> 16);
        if (NU > 64 && second) {
            unsigned t = r[lane + 64];
            c0 += bf2f(t & 0xffffu); c1 += bf2f(t >> 16);
        }
    }
    unsigned* so = (unsigned*)(s + (size_t)wid * (NU * 2));
    so[lane] = (unsigned)f2bf(a0) | ((unsigned)f2bf(a1) << 16);
    if (NU > 64 && second)
        so[lane + 64] = (unsigned)f2bf(c0) | ((unsigned)f2bf(c1) << 16);
}

// ---------------------------------------------------------------------------
// Final projection: half-wave (32 lanes) per vertex, shfl-reduce, N=3.
// ---------------------------------------------------------------------------
__global__ __launch_bounds__(256) void vout_kernel(
    const short* __restrict__ x, const float* __restrict__ W,
    const float* __restrict__ b, float* __restrict__ out)
{
    int w    = (blockIdx.x * blockDim.x + threadIdx.x) >> 6;
    int lane = threadIdx.x & 63;
    int v = w * 2 + (lane >> 5);
    int hl = lane & 31;
    if (v >= V_N) return;
    const unsigned* xr = (const unsigned*)(x + (size_t)v * 128);
    unsigned q0 = xr[hl * 2], q1 = xr[hl * 2 + 1];
    float x0 = bf2f(q0 & 0xffffu), x1 = bf2f(q0 >> 16);
    float x2 = bf2f(q1 & 0xffffu), x3 = bf2f(q1 >> 16);
    int k = hl * 4;
    float a0 = x0 * W[k]       + x1 * W[k + 1]       + x2 * W[k + 2]       + x3 * W[k + 3];
    float a1 = x0 * W[128 + k] + x1 * W[129 + k]     + x2 * W[130 + k]     + x3 * W[131 + k];
    float a2 = x0 * W[256 + k] + x1 * W[257 + k]     + x2 * W[258 + k]     + x3 * W[259 + k];
    #pragma unroll
    for (int off = 1; off < 32; off <<= 1) {
        a0 += __shfl_xor(a0, off);
        a1 += __shfl_xor(a1, off);
        a2 += __shfl_xor(a2, off);
    }
    if (hl == 0) {
        out[3 * v]     = a0 + b[0];
        out[3 * v + 1] = a1 + b[1];
        out[3 * v + 2] = a2 + b[2];
    }
}

// ------------------------- weight / input prep ----------------------------
__global__ void prep_bn_kernel(const float* __restrict__ W, short* __restrict__ Wb)
{
    int i = blockIdx.x * 256 + threadIdx.x;
    if (i < 128 * FEAT) Wb[i] = (short)f2bf(W[i]);
}

// layer0 weights: [128][384]: cols 0..191 = W0 (131 real, pad0), 192..383 = W1
__global__ void prep_w0_kernel(const float* __restrict__ W0,
                               const float* __restrict__ W1,
                               short* __restrict__ Wc)
{
    int i = blockIdx.x * 256 + threadIdx.x;
    if (i >= 128 * 384) return;
    int r = i / 384, c = i % 384;
    float v = 0.f;
    if (c < 192) { if (c < 131) v = W0[r * 131 + c]; }
    else         { int cc = c - 192; if (cc < 131) v = W1[r * 131 + cc]; }
    Wc[i] = (short)f2bf(v);
}

// layers 1..7: [7][128][256]: cols 0..127 = W0, 128..255 = W1
__global__ void prep_wl_kernel(const float* __restrict__ gW0,
                               const float* __restrict__ gW1,
                               short* __restrict__ Wc)
{
    int i = blockIdx.x * 256 + threadIdx.x;
    if (i >= NREST * 128 * 256) return;
    int l = i / (128 * 256), r = (i / 256) % 128, c = i % 256;
    float v = (c < 128) ? gW0[(l * 128 + r) * 128 + c]
                        : gW1[(l * 128 + r) * 128 + (c - 128)];
    Wc[i] = (short)f2bf(v);
}

// x0 cols 128..191: verts at 128..130, zeros elsewhere. 8 threads/row, uint4.
__global__ void pad_x0_kernel(const float* __restrict__ verts, short* __restrict__ x0)
{
    int i = blockIdx.x * 256 + threadIdx.x;
    int v = i >> 3, c8 = i & 7;
    if (v >= V_N) return;
    unsigned short h[8] = {0, 0, 0, 0, 0, 0, 0, 0};
    if (c8 == 0) {
        h[0] = f2bf(verts[3 * v]);
        h[1] = f2bf(verts[3 * v + 1]);
        h[2] = f2bf(verts[3 * v + 2]);
    }
    *(uint4*)(x0 + (size_t)v * 192 + 128 + c8 * 8) = *(const uint4*)h;
}

// ------------------------- CSR construction -------------------------------
__global__ void deg_count_kernel(const int* __restrict__ edges, int* __restrict__ deg)
{
    int e = blockIdx.x * blockDim.x + threadIdx.x;
    if (e >= E_N) return;
    int i = edges[2 * e], j = edges[2 * e + 1];
    atomicAdd(&deg[i], 1);
    atomicAdd(&deg[j], 1);
}

__global__ __launch_bounds__(1024) void scan_block_kernel(
    const int* __restrict__ deg, int* __restrict__ excl, int* __restrict__ bsum)
{
    __shared__ int sdata[1024];
    int t = threadIdx.x;
    int base = blockIdx.x * 1024;
    int val = (base + t < V_N) ? deg[base + t] : 0;
    sdata[t] = val; __syncthreads();
    for (int off = 1; off < 1024; off <<= 1) {
        int tmp = (t >= off) ? sdata[t - off] : 0;
        __syncthreads();
        sdata[t] += tmp;
        __syncthreads();
    }
    if (base + t < V_N) excl[base + t] = sdata[t] - val;
    if (t == 1023) bsum[blockIdx.x] = sdata[1023];
}

__global__ __launch_bounds__(256) void scan_bsum_kernel(
    const int* __restrict__ bsum, int* __restrict__ boff)
{
    __shared__ int sdata[256];
    int t = threadIdx.x;
    int val = (t < NSCAN) ? bsum[t] : 0;
    sdata[t] = val; __syncthreads();
    for (int off = 1; off < 256; off <<= 1) {
        int tmp = (t >= off) ? sdata[t - off] : 0;
        __syncthreads();
        sdata[t] += tmp;
        __syncthreads();
    }
    if (t < NSCAN) boff[t] = sdata[t] - val;
    if (t == 255) boff[NSCAN] = sdata[255];
}

__global__ void scan_add_kernel(const int* __restrict__ boff,
                                int* __restrict__ rowp, int* __restrict__ cur)
{
    int i = blockIdx.x * blockDim.x + threadIdx.x;
    if (i < V_N) {
        int r = rowp[i] + boff[i >> 10];
        rowp[i] = r;
        cur[i] = r;
    } else if (i == V_N) {
        rowp[V_N] = boff[NSCAN];
    }
}

__global__ void fill_kernel(const int* __restrict__ edges,
                            int* __restrict__ cur, int* __restrict__ col)
{
    int e = blockIdx.x * blockDim.x + threadIdx.x;
    if (e >= E_N) return;
    int i = edges[2 * e], j = edges[2 * e + 1];
    col[atomicAdd(&cur[i], 1)] = j;
    col[atomicAdd(&cur[j], 1)] = i;
}

// ---------------------------------------------------------------------------
extern "C" void kernel_launch(void* const* d_in, const int* in_sizes, int n_in,
                              void* d_out, int out_size, void* d_ws, size_t ws_size,
                              hipStream_t stream)
{
    const float* img   = (const float*)d_in[0];
    const float* verts = (const float*)d_in[1];
    const int*   edges = (const int*)  d_in[2];
    const float* bnW   = (const float*)d_in[3];
    const float* bnb   = (const float*)d_in[4];
    const float* g0W0  = (const float*)d_in[5];
    const float* g0b0  = (const float*)d_in[6];
    const float* g0W1  = (const float*)d_in[7];
    const float* g0b1  = (const float*)d_in[8];
    const float* gW0   = (const float*)d_in[9];
    const float* gb0   = (const float*)d_in[10];
    const float* gW1   = (const float*)d_in[11];
    const float* gb1   = (const float*)d_in[12];
    const float* voW   = (const float*)d_in[13];
    const float* vob   = (const float*)d_in[14];
    float* out = (float*)d_out;

    // workspace layout (all segment byte counts multiples of 16)
    short* x0   = (short*)d_ws;                       // V*192 bf16
    short* s0   = x0   + (size_t)V_N * 192;           // V*192 bf16
    short* xb   = s0   + (size_t)V_N * 192;           // V*128 bf16
    short* sb   = xb   + (size_t)V_N * 128;           // V*128 bf16
    short* bnWb = sb   + (size_t)V_N * 128;           // 128*960
    short* Wc0  = bnWb + 128 * FEAT;                  // 128*384
    short* Wcl  = Wc0  + 128 * 384;                   // 7*128*256
    int*   deg  = (int*)(Wcl + NREST * 128 * 256);    // V
    int*   rowp = deg  + V_N;                         // V+1
    int*   cur  = rowp + V_N + 1;                     // V
    int*   bsum = cur  + V_N;                         // 256
    int*   boff = bsum + 256;                         // NSCAN+1
    int*   col  = boff + 257;                         // 2E

    // ---- CSR build ----
    hipMemsetAsync(deg, 0, V_N * sizeof(int), stream);
    deg_count_kernel<<<(E_N + 255) / 256, 256, 0, stream>>>(edges, deg);
    scan_block_kernel<<<NSCAN, 1024, 0, stream>>>(deg, rowp, bsum);
    scan_bsum_kernel<<<1, 256, 0, stream>>>(bsum, boff);
    scan_add_kernel<<<(V_N + 256) / 256, 256, 0, stream>>>(boff, rowp, cur);
    fill_kernel<<<(E_N + 255) / 256, 256, 0, stream>>>(edges, cur, col);

    // ---- weight / x0 prep ----
    prep_bn_kernel<<<(128 * FEAT + 255) / 256, 256, 0, stream>>>(bnW, bnWb);
    prep_w0_kernel<<<(128 * 384 + 255) / 256, 256, 0, stream>>>(g0W0, g0W1, Wc0);
    prep_wl_kernel<<<(NREST * 128 * 256 + 255) / 256, 256, 0, stream>>>(gW0, gW1, Wcl);
    pad_x0_kernel<<<(V_N * 8 + 255) / 256, 256, 0, stream>>>(verts, x0);

    const int MB = (V_N + 127) / 128;   // 1563

    // ---- backbone: img(fp32,K=960) @ bnW^T -> x0 cols 0..127 (relu) ----
    backbone_mfma_kernel<15><<<MB, 256, 0, stream>>>(img, FEAT, bnWb, FEAT, bnb, x0, 192);

    // ---- layer 0 ----
    agg_sum_kernel<96><<<(V_N * 64 + 255) / 256, 256, 0, stream>>>(x0, rowp, col, s0);
    gconv_mfma_kernel<3, 3><<<MB, 256, 0, stream>>>(
        x0, 192, s0, 192, Wc0, g0b0, g0b1, deg, xb);

    // ---- layers 1..7 (GEMM in-place on xb) ----
    for (int l = 0; l < NREST; ++l) {
        agg_sum_kernel<64><<<(V_N * 64 + 255) / 256, 256, 0, stream>>>(xb, rowp, col, sb);
        gconv_mfma_kernel<2, 2><<<MB, 256, 0, stream>>>(
            xb, 128, sb, 128, Wcl + (size_t)l * 128 * 256,
            gb0 + (size_t)l * 128, gb1 + (size_t)l * 128, deg, xb);
    }

    // ---- final projection ----
    vout_kernel<<<(V_N * 32 + 255) / 256, 256, 0, stream>>>(xb, voW, vob, out);
}